// Round 8
// baseline (606.147 us; speedup 1.0000x reference)
//
#include <hip/hip_runtime.h>

#define N_NODES 100000
#define N_EDGES 3200000
#define F_IN    512
#define HIDDEN  16
#define N_CLASS 10

#define NBUCK   196       // dst buckets of 512 nodes: 196*512 = 100352 >= N_NODES
#define BSH     9         // bucket shift (512 nodes)
#define EPB     4096      // edges per partition block
#define NPART   ((N_EDGES + EPB - 1) / EPB)   // 782
#define PCAP    18432     // LDS staging cap per bucket (mean 16326 + 16 sigma; guarded fallback)

// index load robust to int32/int64 (is32 nonzero => int32)
__device__ __forceinline__ int load_idx(const void* ei, int is32, long long pos) {
    return is32 ? ((const int*)ei)[pos] : (int)((const long long*)ei)[pos];
}

// merged init: zero bucket sizes + int32/int64 probe (single block)
__global__ void k_init(const unsigned* __restrict__ ei, int* __restrict__ bsize,
                       int* __restrict__ det) {
    int t = threadIdx.x;
    if (t < NBUCK) bsize[t] = 0;
    if (t == 0) det[0] = 0;
    __syncthreads();
    unsigned odd = 0;
    for (int i = t; i < 4096; i += 256) odd |= ei[2 * i + 1];   // 32KB read, safe either way
    if (odd) atomicOr(&det[0], 1);
}

// per-block LDS histogram of dst buckets -> global bucket sizes
__global__ __launch_bounds__(256) void k_bhist(const void* __restrict__ ei,
                                               const int* __restrict__ det,
                                               int* __restrict__ bsize) {
    __shared__ int hist[NBUCK];
    int t = threadIdx.x;
    long long e0 = (long long)blockIdx.x * EPB;
    long long e1 = e0 + EPB; if (e1 > N_EDGES) e1 = N_EDGES;
    int is32 = det[0];
    if (t < NBUCK) hist[t] = 0;
    __syncthreads();
    for (long long e = e0 + t; e < e1; e += 256) {
        int d = load_idx(ei, is32, N_EDGES + e);
        atomicAdd(&hist[d >> BSH], 1);
    }
    __syncthreads();
    if (t < NBUCK && hist[t]) atomicAdd(&bsize[t], hist[t]);
}

// exclusive scan of 196 bucket sizes -> bbase (read-only) and bcur (atomic cursors)
__global__ void k_bucketscan(const int* __restrict__ bsize, int* __restrict__ bbase,
                             int* __restrict__ bcur) {
    __shared__ int s[256];
    int t = threadIdx.x;
    int v = (t < NBUCK) ? bsize[t] : 0;
    s[t] = v;
    __syncthreads();
    for (int off = 1; off < 256; off <<= 1) {
        int u = (t >= off) ? s[t - off] : 0;
        __syncthreads();
        s[t] += u;
        __syncthreads();
    }
    if (t < NBUCK) { int ex = s[t] - v; bbase[t] = ex; bcur[t] = ex; }
}

// partition edges into dst buckets; packed word = (s<<9)|(d&511) (26 bits)
__global__ __launch_bounds__(256) void k_part(const void* __restrict__ ei,
                                              const int* __restrict__ det,
                                              int* __restrict__ bcur,
                                              unsigned* __restrict__ buf) {
    __shared__ int hist[NBUCK];
    __shared__ int base[NBUCK];
    __shared__ int lcur[NBUCK];
    int t = threadIdx.x;
    long long e0 = (long long)blockIdx.x * EPB;
    long long e1 = e0 + EPB; if (e1 > N_EDGES) e1 = N_EDGES;
    int is32 = det[0];
    if (t < NBUCK) { hist[t] = 0; lcur[t] = 0; }
    __syncthreads();
    for (long long e = e0 + t; e < e1; e += 256) {
        int d = load_idx(ei, is32, N_EDGES + e);
        atomicAdd(&hist[d >> BSH], 1);
    }
    __syncthreads();
    if (t < NBUCK) base[t] = hist[t] ? atomicAdd(&bcur[t], hist[t]) : 0;
    __syncthreads();
    for (long long e = e0 + t; e < e1; e += 256) {
        int s = load_idx(ei, is32, e);
        int d = load_idx(ei, is32, (long long)N_EDGES + e);
        int b = d >> BSH;
        int off = atomicAdd(&lcur[b], 1);
        buf[base[b] + off] = ((unsigned)s << BSH) | (unsigned)(d & 511);
    }
}

// per-bucket degree histogram + in-LDS 512-wide scan -> rowptr AND dinv in one pass.
// Invariant: bbase[b] == rowptr[b<<BSH] (both prefix-sum the same per-bucket counts),
// so rowptr[n] = bbase[b] + exclusive_prefix_within_bucket(n).
__global__ __launch_bounds__(256) void k_degscan(const unsigned* __restrict__ buf,
                                                 const int* __restrict__ bbase,
                                                 const int* __restrict__ bsize,
                                                 int* __restrict__ rowptr,
                                                 float* __restrict__ dinv) {
    __shared__ int s[512];
    int t = threadIdx.x;
    int b = blockIdx.x;
    s[t] = 0; s[t + 256] = 0;
    __syncthreads();
    int j0 = bbase[b], j1 = j0 + bsize[b];
    for (int j = j0 + t; j < j1; j += 256)
        atomicAdd(&s[buf[j] & 511], 1);
    __syncthreads();
    int o0 = s[t], o1 = s[t + 256];
    // inclusive Hillis-Steele over 512 elems, 2 per thread (read-all / barrier / write-all)
    for (int off = 1; off < 512; off <<= 1) {
        int v0 = (t >= off) ? s[t - off] : 0;
        int v1 = s[t + 256 - off];           // t+256 >= off always (off <= 256)
        __syncthreads();
        s[t] += v0; s[t + 256] += v1;
        __syncthreads();
    }
    int nb0 = b << BSH;
    int base = bbase[b];
    int n0 = nb0 + t, n1 = nb0 + t + 256;
    if (n0 < N_NODES) { rowptr[n0] = base + s[t] - o0;       dinv[n0] = rsqrtf((float)(o0 + 1)); }
    if (n1 < N_NODES) { rowptr[n1] = base + s[t + 256] - o1; dinv[n1] = rsqrtf((float)(o1 + 1)); }
    if (b == NBUCK - 1 && t == 0) rowptr[N_NODES] = N_EDGES;
}

// CSR placement with LDS staging: one block per bucket.
// Positions resolved via LDS cursors (rowptr[n]-csrbase), src scattered into an LDS
// buffer, then streamed to csr with fully-coalesced stores.
__global__ __launch_bounds__(256) void k_place3(const unsigned* __restrict__ buf,
                                                const int* __restrict__ bbase,
                                                const int* __restrict__ bsize,
                                                const int* __restrict__ rowptr,
                                                int* __restrict__ csr) {
    __shared__ int lptr[512];
    __shared__ int outb[PCAP];
    int t = threadIdx.x;
    int b = blockIdx.x;
    int jb = bbase[b];           // buf segment base
    int sz = bsize[b];
    int nb0 = b << BSH;
    int csrbase = rowptr[nb0];   // == jb
    for (int i = t; i < 512; i += 256) {
        int n = nb0 + i;
        lptr[i] = (n < N_NODES) ? rowptr[n] - csrbase : sz;
    }
    __syncthreads();
    for (int j = t; j < sz; j += 256) {
        unsigned p = buf[jb + j];
        int pos = atomicAdd(&lptr[p & 511], 1);
        int s = (int)(p >> BSH);
        if (pos < PCAP) outb[pos] = s;
        else            csr[csrbase + pos] = s;   // statistically unreachable fallback
    }
    __syncthreads();
    int lim = sz < PCAP ? sz : PCAP;
    for (int j = t; j < lim; j += 256) csr[csrbase + j] = outb[j];
}

// hs[N][16] = (x @ W1) * dinv[row].  Thread-per-row register GEMV, no LDS, no barriers.
// Per chunk: 16 float4 loads in flight (4 x 64B lines deep per lane), then 1024 FMAs.
// W1 accesses are wave-uniform -> scalar cache.
__global__ __launch_bounds__(128) void k_gemv1(const float* __restrict__ x,
                                               const float* __restrict__ W1,
                                               const float* __restrict__ dinv,
                                               float* __restrict__ hs) {
    int n = blockIdx.x * 128 + threadIdx.x;
    if (n >= N_NODES) return;
    const float4* xr = (const float4*)(x + (size_t)n * F_IN);
    float acc[16];
#pragma unroll
    for (int k = 0; k < 16; ++k) acc[k] = 0.f;
#pragma unroll 1
    for (int ch = 0; ch < F_IN / 64; ++ch) {
        float4 v[16];
#pragma unroll
        for (int i = 0; i < 16; ++i) v[i] = xr[ch * 16 + i];
#pragma unroll
        for (int i = 0; i < 16; ++i) {
            const float* wp = &W1[(ch * 64 + i * 4) * HIDDEN];
#pragma unroll
            for (int k = 0; k < 16; ++k)
                acc[k] += v[i].x * wp[k]      + v[i].y * wp[16 + k]
                        + v[i].z * wp[32 + k] + v[i].w * wp[48 + k];
        }
    }
    float di = dinv[n];
    float4* o = (float4*)&hs[(size_t)n * HIDDEN];
    o[0] = make_float4(acc[0] * di,  acc[1] * di,  acc[2] * di,  acc[3] * di);
    o[1] = make_float4(acc[4] * di,  acc[5] * di,  acc[6] * di,  acc[7] * di);
    o[2] = make_float4(acc[8] * di,  acc[9] * di,  acc[10] * di, acc[11] * di);
    o[3] = make_float4(acc[12] * di, acc[13] * di, acc[14] * di, acc[15] * di);
}

// layer-1 gather-aggregate (atomic-free) + bias + ReLU + (16->10)W2 + dinv pre-scale
__global__ __launch_bounds__(256) void k_agg1(const int* __restrict__ rowptr,
                                              const int* __restrict__ csr,
                                              const float* __restrict__ hs,
                                              const float* __restrict__ dinv,
                                              const float* __restrict__ b1,
                                              const float* __restrict__ W2,
                                              float* __restrict__ ts) {
    __shared__ float sh[16][17];
    int t  = threadIdx.x;
    int ln = t >> 4;          // local node 0..15
    int k  = t & 15;          // feature lane
    int n  = blockIdx.x * 16 + ln;
    bool valid = n < N_NODES;
    int r0 = valid ? rowptr[n] : 0;
    int r1 = valid ? rowptr[n + 1] : 0;
    float acc = valid ? hs[(size_t)n * HIDDEN + k] : 0.f;   // self-loop (already *dinv[n])
    int j = r0;
    for (; j + 4 <= r1; j += 4) {
        int s0 = csr[j], s1 = csr[j + 1], s2 = csr[j + 2], s3 = csr[j + 3];
        float v0 = hs[(size_t)s0 * HIDDEN + k];
        float v1 = hs[(size_t)s1 * HIDDEN + k];
        float v2 = hs[(size_t)s2 * HIDDEN + k];
        float v3 = hs[(size_t)s3 * HIDDEN + k];
        acc += (v0 + v1) + (v2 + v3);
    }
    for (; j < r1; ++j) acc += hs[(size_t)csr[j] * HIDDEN + k];
    float di = valid ? dinv[n] : 0.f;
    float h = di * acc + b1[k];
    sh[ln][k] = h > 0.f ? h : 0.f;
    __syncthreads();
    int c = (k < N_CLASS) ? k : 0;
    float o = 0.f;
#pragma unroll
    for (int kk = 0; kk < HIDDEN; ++kk) o += sh[ln][kk] * W2[kk * N_CLASS + c];
    if (valid) ts[(size_t)n * 16 + k] = (k < N_CLASS) ? o * di : 0.f;
}

// layer-2 gather-aggregate (atomic-free) + bias -> out
__global__ __launch_bounds__(256) void k_agg2(const int* __restrict__ rowptr,
                                              const int* __restrict__ csr,
                                              const float* __restrict__ ts,
                                              const float* __restrict__ dinv,
                                              const float* __restrict__ b2,
                                              float* __restrict__ out) {
    int t  = threadIdx.x;
    int ln = t >> 4;
    int c  = t & 15;
    int n  = blockIdx.x * 16 + ln;
    if (n >= N_NODES) return;
    int r0 = rowptr[n], r1 = rowptr[n + 1];
    float acc = ts[(size_t)n * 16 + c];    // self-loop (already *dinv[n])
    int j = r0;
    for (; j + 4 <= r1; j += 4) {
        int s0 = csr[j], s1 = csr[j + 1], s2 = csr[j + 2], s3 = csr[j + 3];
        float v0 = ts[(size_t)s0 * 16 + c];
        float v1 = ts[(size_t)s1 * 16 + c];
        float v2 = ts[(size_t)s2 * 16 + c];
        float v3 = ts[(size_t)s3 * 16 + c];
        acc += (v0 + v1) + (v2 + v3);
    }
    for (; j < r1; ++j) acc += ts[(size_t)csr[j] * 16 + c];
    if (c < N_CLASS) out[(size_t)n * N_CLASS + c] = dinv[n] * acc + b2[c];
}

extern "C" void kernel_launch(void* const* d_in, const int* in_sizes, int n_in,
                              void* d_out, int out_size, void* d_ws, size_t ws_size,
                              hipStream_t stream) {
    const float* x  = (const float*)d_in[0];   // fp32 [N,512]
    const void*  ei = d_in[1];                 // int64 (int32 handled via probe)
    const float* W1 = (const float*)d_in[2];   // fp32 [512,16]
    const float* b1 = (const float*)d_in[3];   // fp32 [16]
    const float* W2 = (const float*)d_in[4];   // fp32 [16,10]
    const float* b2 = (const float*)d_in[5];   // fp32 [10]
    float* out = (float*)d_out;                // fp32 [N,10]
    float* ws  = (float*)d_ws;

    // ws layout (4-byte units), ~26.4 MB total
    float* dinv   = ws;                        // 100,096
    int*   rowptr = (int*)(ws + 100096);       // 100,416  (N+1, padded)
    int*   bsize  = (int*)(ws + 200512);       // 256
    int*   bbase  = (int*)(ws + 200768);       // 256
    int*   bcur   = (int*)(ws + 201024);       // 256
    int*   det    = (int*)(ws + 201280);       // 64
    int*   csr    = (int*)(ws + 201344);       // 3,200,000
    float* hs     = ws + 3401344;              // 1,600,000
    float* ts     = ws + 5001344;              // 1,600,000
    // buf (3.2M uint32) overlays hs+ts: dead after k_place3, before k_gemv1 writes hs
    unsigned* buf = (unsigned*)(ws + 3401344);

    k_init      <<<1, 256, 0, stream>>>((const unsigned*)ei, bsize, det);
    k_bhist     <<<NPART, 256, 0, stream>>>(ei, det, bsize);
    k_bucketscan<<<1, 256, 0, stream>>>(bsize, bbase, bcur);
    k_part      <<<NPART, 256, 0, stream>>>(ei, det, bcur, buf);
    k_degscan   <<<NBUCK, 256, 0, stream>>>(buf, bbase, bsize, rowptr, dinv);
    k_place3    <<<NBUCK, 256, 0, stream>>>(buf, bbase, bsize, rowptr, csr);

    k_gemv1<<<(N_NODES + 127) / 128, 128, 0, stream>>>(x, W1, dinv, hs);

    k_agg1<<<(N_NODES + 15) / 16, 256, 0, stream>>>(rowptr, csr, hs, dinv, b1, W2, ts);
    k_agg2<<<(N_NODES + 15) / 16, 256, 0, stream>>>(rowptr, csr, ts, dinv, b2, out);
}

// Round 9
// 585.635 us; speedup vs baseline: 1.0350x; 1.0350x over previous
//
#include <hip/hip_runtime.h>

#define N_NODES 100000
#define N_EDGES 3200000
#define F_IN    512
#define HIDDEN  16
#define N_CLASS 10

#define NBUCK   196       // dst buckets of 512 nodes: 196*512 = 100352 >= N_NODES
#define BSH     9         // bucket shift (512 nodes)
#define EPB     4096      // edges per partition block
#define NPART   ((N_EDGES + EPB - 1) / EPB)   // 782
#define PCAP    18432     // LDS staging cap per bucket (mean 16326 + 16 sigma; guarded fallback)

// index load robust to int32/int64 (is32 nonzero => int32)
__device__ __forceinline__ int load_idx(const void* ei, int is32, long long pos) {
    return is32 ? ((const int*)ei)[pos] : (int)((const long long*)ei)[pos];
}

// merged init: zero bucket sizes + int32/int64 probe (single block)
__global__ void k_init(const unsigned* __restrict__ ei, int* __restrict__ bsize,
                       int* __restrict__ det) {
    int t = threadIdx.x;
    if (t < NBUCK) bsize[t] = 0;
    if (t == 0) det[0] = 0;
    __syncthreads();
    unsigned odd = 0;
    for (int i = t; i < 4096; i += 256) odd |= ei[2 * i + 1];   // 32KB read, safe either way
    if (odd) atomicOr(&det[0], 1);
}

// per-block LDS histogram of dst buckets -> global bucket sizes
__global__ __launch_bounds__(256) void k_bhist(const void* __restrict__ ei,
                                               const int* __restrict__ det,
                                               int* __restrict__ bsize) {
    __shared__ int hist[NBUCK];
    int t = threadIdx.x;
    long long e0 = (long long)blockIdx.x * EPB;
    long long e1 = e0 + EPB; if (e1 > N_EDGES) e1 = N_EDGES;
    int is32 = det[0];
    if (t < NBUCK) hist[t] = 0;
    __syncthreads();
    for (long long e = e0 + t; e < e1; e += 256) {
        int d = load_idx(ei, is32, N_EDGES + e);
        atomicAdd(&hist[d >> BSH], 1);
    }
    __syncthreads();
    if (t < NBUCK && hist[t]) atomicAdd(&bsize[t], hist[t]);
}

// exclusive scan of 196 bucket sizes -> bbase (read-only) and bcur (atomic cursors)
__global__ void k_bucketscan(const int* __restrict__ bsize, int* __restrict__ bbase,
                             int* __restrict__ bcur) {
    __shared__ int s[256];
    int t = threadIdx.x;
    int v = (t < NBUCK) ? bsize[t] : 0;
    s[t] = v;
    __syncthreads();
    for (int off = 1; off < 256; off <<= 1) {
        int u = (t >= off) ? s[t - off] : 0;
        __syncthreads();
        s[t] += u;
        __syncthreads();
    }
    if (t < NBUCK) { int ex = s[t] - v; bbase[t] = ex; bcur[t] = ex; }
}

// partition edges into dst buckets; packed word = (s<<9)|(d&511) (26 bits)
__global__ __launch_bounds__(256) void k_part(const void* __restrict__ ei,
                                              const int* __restrict__ det,
                                              int* __restrict__ bcur,
                                              unsigned* __restrict__ buf) {
    __shared__ int hist[NBUCK];
    __shared__ int base[NBUCK];
    __shared__ int lcur[NBUCK];
    int t = threadIdx.x;
    long long e0 = (long long)blockIdx.x * EPB;
    long long e1 = e0 + EPB; if (e1 > N_EDGES) e1 = N_EDGES;
    int is32 = det[0];
    if (t < NBUCK) { hist[t] = 0; lcur[t] = 0; }
    __syncthreads();
    for (long long e = e0 + t; e < e1; e += 256) {
        int d = load_idx(ei, is32, N_EDGES + e);
        atomicAdd(&hist[d >> BSH], 1);
    }
    __syncthreads();
    if (t < NBUCK) base[t] = hist[t] ? atomicAdd(&bcur[t], hist[t]) : 0;
    __syncthreads();
    for (long long e = e0 + t; e < e1; e += 256) {
        int s = load_idx(ei, is32, e);
        int d = load_idx(ei, is32, (long long)N_EDGES + e);
        int b = d >> BSH;
        int off = atomicAdd(&lcur[b], 1);
        buf[base[b] + off] = ((unsigned)s << BSH) | (unsigned)(d & 511);
    }
}

// per-bucket degree histogram + in-LDS 512-wide scan -> rowptr AND dinv in one pass.
// Invariant: bbase[b] == rowptr[b<<BSH] (both prefix-sum the same per-bucket counts).
__global__ __launch_bounds__(256) void k_degscan(const unsigned* __restrict__ buf,
                                                 const int* __restrict__ bbase,
                                                 const int* __restrict__ bsize,
                                                 int* __restrict__ rowptr,
                                                 float* __restrict__ dinv) {
    __shared__ int s[512];
    int t = threadIdx.x;
    int b = blockIdx.x;
    s[t] = 0; s[t + 256] = 0;
    __syncthreads();
    int j0 = bbase[b], j1 = j0 + bsize[b];
    for (int j = j0 + t; j < j1; j += 256)
        atomicAdd(&s[buf[j] & 511], 1);
    __syncthreads();
    int o0 = s[t], o1 = s[t + 256];
    // inclusive Hillis-Steele over 512 elems, 2 per thread (read-all / barrier / write-all)
    for (int off = 1; off < 512; off <<= 1) {
        int v0 = (t >= off) ? s[t - off] : 0;
        int v1 = s[t + 256 - off];           // t+256 >= off always (off <= 256)
        __syncthreads();
        s[t] += v0; s[t + 256] += v1;
        __syncthreads();
    }
    int nb0 = b << BSH;
    int base = bbase[b];
    int n0 = nb0 + t, n1 = nb0 + t + 256;
    if (n0 < N_NODES) { rowptr[n0] = base + s[t] - o0;       dinv[n0] = rsqrtf((float)(o0 + 1)); }
    if (n1 < N_NODES) { rowptr[n1] = base + s[t + 256] - o1; dinv[n1] = rsqrtf((float)(o1 + 1)); }
    if (b == NBUCK - 1 && t == 0) rowptr[N_NODES] = N_EDGES;
}

// CSR placement with LDS staging: one block per bucket; coalesced csr stores.
__global__ __launch_bounds__(256) void k_place3(const unsigned* __restrict__ buf,
                                                const int* __restrict__ bbase,
                                                const int* __restrict__ bsize,
                                                const int* __restrict__ rowptr,
                                                int* __restrict__ csr) {
    __shared__ int lptr[512];
    __shared__ int outb[PCAP];
    int t = threadIdx.x;
    int b = blockIdx.x;
    int jb = bbase[b];           // buf segment base
    int sz = bsize[b];
    int nb0 = b << BSH;
    int csrbase = rowptr[nb0];   // == jb
    for (int i = t; i < 512; i += 256) {
        int n = nb0 + i;
        lptr[i] = (n < N_NODES) ? rowptr[n] - csrbase : sz;
    }
    __syncthreads();
    for (int j = t; j < sz; j += 256) {
        unsigned p = buf[jb + j];
        int pos = atomicAdd(&lptr[p & 511], 1);
        int s = (int)(p >> BSH);
        if (pos < PCAP) outb[pos] = s;
        else            csr[csrbase + pos] = s;   // statistically unreachable fallback
    }
    __syncthreads();
    int lim = sz < PCAP ? sz : PCAP;
    for (int j = t; j < lim; j += 256) csr[csrbase + j] = outb[j];
}

// hs[N][16] = (x @ W1) * dinv[row].
// 4 threads per row (128 features each) -> 400K threads, ~6 waves/SIMD (was 1.5).
// Wave w of each block == segment w, so W1 accesses stay wave-uniform (scalar cache).
// 8 chunks of 4xfloat4 with register prefetch: chunk ch+1's loads issue before ch's FMAs.
// 3 partial sums reduced via padded LDS (stride 17 -> 2-way = free).
__global__ __launch_bounds__(256) void k_gemv1(const float* __restrict__ x,
                                               const float* __restrict__ W1,
                                               const float* __restrict__ dinv,
                                               float* __restrict__ hs) {
    __shared__ float red[3][64][17];
    int t = threadIdx.x;
    int r = t & 63;            // row within block
    int seg = t >> 6;          // feature segment 0..3 == wave id
    int n = blockIdx.x * 64 + r;
    bool valid = n < N_NODES;
    const float4* xr = (const float4*)(x + (valid ? (size_t)n * F_IN : 0) + seg * 128);
    float acc[16];
#pragma unroll
    for (int k = 0; k < 16; ++k) acc[k] = 0.f;
    float4 cur0 = xr[0], cur1 = xr[1], cur2 = xr[2], cur3 = xr[3];
#pragma unroll 1
    for (int ch = 0; ch < 8; ++ch) {
        float4 nx0, nx1, nx2, nx3;
        if (ch < 7) {
            nx0 = xr[(ch + 1) * 4 + 0]; nx1 = xr[(ch + 1) * 4 + 1];
            nx2 = xr[(ch + 1) * 4 + 2]; nx3 = xr[(ch + 1) * 4 + 3];
        }
        const float* wp = W1 + (seg * 128 + ch * 16) * HIDDEN;   // wave-uniform
#pragma unroll
        for (int k = 0; k < 16; ++k)
            acc[k] += cur0.x * wp[0 * 16 + k] + cur0.y * wp[1 * 16 + k]
                    + cur0.z * wp[2 * 16 + k] + cur0.w * wp[3 * 16 + k];
#pragma unroll
        for (int k = 0; k < 16; ++k)
            acc[k] += cur1.x * wp[4 * 16 + k] + cur1.y * wp[5 * 16 + k]
                    + cur1.z * wp[6 * 16 + k] + cur1.w * wp[7 * 16 + k];
#pragma unroll
        for (int k = 0; k < 16; ++k)
            acc[k] += cur2.x * wp[8 * 16 + k] + cur2.y * wp[9 * 16 + k]
                    + cur2.z * wp[10 * 16 + k] + cur2.w * wp[11 * 16 + k];
#pragma unroll
        for (int k = 0; k < 16; ++k)
            acc[k] += cur3.x * wp[12 * 16 + k] + cur3.y * wp[13 * 16 + k]
                    + cur3.z * wp[14 * 16 + k] + cur3.w * wp[15 * 16 + k];
        if (ch < 7) { cur0 = nx0; cur1 = nx1; cur2 = nx2; cur3 = nx3; }
    }
    if (seg) {
#pragma unroll
        for (int k = 0; k < 16; ++k) red[seg - 1][r][k] = acc[k];
    }
    __syncthreads();
    if (seg == 0 && valid) {
#pragma unroll
        for (int k = 0; k < 16; ++k)
            acc[k] += red[0][r][k] + red[1][r][k] + red[2][r][k];
        float di = dinv[n];
        float4* o = (float4*)&hs[(size_t)n * HIDDEN];
        o[0] = make_float4(acc[0] * di,  acc[1] * di,  acc[2] * di,  acc[3] * di);
        o[1] = make_float4(acc[4] * di,  acc[5] * di,  acc[6] * di,  acc[7] * di);
        o[2] = make_float4(acc[8] * di,  acc[9] * di,  acc[10] * di, acc[11] * di);
        o[3] = make_float4(acc[12] * di, acc[13] * di, acc[14] * di, acc[15] * di);
    }
}

// layer-1 gather-aggregate (atomic-free) + bias + ReLU + (16->10)W2 + dinv pre-scale.
// 8-deep gather unroll: 8 independent L2/L3 loads in flight per 16-lane group.
__global__ __launch_bounds__(256) void k_agg1(const int* __restrict__ rowptr,
                                              const int* __restrict__ csr,
                                              const float* __restrict__ hs,
                                              const float* __restrict__ dinv,
                                              const float* __restrict__ b1,
                                              const float* __restrict__ W2,
                                              float* __restrict__ ts) {
    __shared__ float sh[16][17];
    int t  = threadIdx.x;
    int ln = t >> 4;          // local node 0..15
    int k  = t & 15;          // feature lane
    int n  = blockIdx.x * 16 + ln;
    bool valid = n < N_NODES;
    int r0 = valid ? rowptr[n] : 0;
    int r1 = valid ? rowptr[n + 1] : 0;
    float acc = valid ? hs[(size_t)n * HIDDEN + k] : 0.f;   // self-loop (already *dinv[n])
    int j = r0;
    for (; j + 8 <= r1; j += 8) {
        int s0 = csr[j],     s1 = csr[j + 1], s2 = csr[j + 2], s3 = csr[j + 3];
        int s4 = csr[j + 4], s5 = csr[j + 5], s6 = csr[j + 6], s7 = csr[j + 7];
        float v0 = hs[(size_t)s0 * HIDDEN + k];
        float v1 = hs[(size_t)s1 * HIDDEN + k];
        float v2 = hs[(size_t)s2 * HIDDEN + k];
        float v3 = hs[(size_t)s3 * HIDDEN + k];
        float v4 = hs[(size_t)s4 * HIDDEN + k];
        float v5 = hs[(size_t)s5 * HIDDEN + k];
        float v6 = hs[(size_t)s6 * HIDDEN + k];
        float v7 = hs[(size_t)s7 * HIDDEN + k];
        acc += ((v0 + v1) + (v2 + v3)) + ((v4 + v5) + (v6 + v7));
    }
    for (; j + 4 <= r1; j += 4) {
        int s0 = csr[j], s1 = csr[j + 1], s2 = csr[j + 2], s3 = csr[j + 3];
        float v0 = hs[(size_t)s0 * HIDDEN + k];
        float v1 = hs[(size_t)s1 * HIDDEN + k];
        float v2 = hs[(size_t)s2 * HIDDEN + k];
        float v3 = hs[(size_t)s3 * HIDDEN + k];
        acc += (v0 + v1) + (v2 + v3);
    }
    for (; j < r1; ++j) acc += hs[(size_t)csr[j] * HIDDEN + k];
    float di = valid ? dinv[n] : 0.f;
    float h = di * acc + b1[k];
    sh[ln][k] = h > 0.f ? h : 0.f;
    __syncthreads();
    int c = (k < N_CLASS) ? k : 0;
    float o = 0.f;
#pragma unroll
    for (int kk = 0; kk < HIDDEN; ++kk) o += sh[ln][kk] * W2[kk * N_CLASS + c];
    if (valid) ts[(size_t)n * 16 + k] = (k < N_CLASS) ? o * di : 0.f;
}

// layer-2 gather-aggregate (atomic-free) + bias -> out
__global__ __launch_bounds__(256) void k_agg2(const int* __restrict__ rowptr,
                                              const int* __restrict__ csr,
                                              const float* __restrict__ ts,
                                              const float* __restrict__ dinv,
                                              const float* __restrict__ b2,
                                              float* __restrict__ out) {
    int t  = threadIdx.x;
    int ln = t >> 4;
    int c  = t & 15;
    int n  = blockIdx.x * 16 + ln;
    if (n >= N_NODES) return;
    int r0 = rowptr[n], r1 = rowptr[n + 1];
    float acc = ts[(size_t)n * 16 + c];    // self-loop (already *dinv[n])
    int j = r0;
    for (; j + 8 <= r1; j += 8) {
        int s0 = csr[j],     s1 = csr[j + 1], s2 = csr[j + 2], s3 = csr[j + 3];
        int s4 = csr[j + 4], s5 = csr[j + 5], s6 = csr[j + 6], s7 = csr[j + 7];
        float v0 = ts[(size_t)s0 * 16 + c];
        float v1 = ts[(size_t)s1 * 16 + c];
        float v2 = ts[(size_t)s2 * 16 + c];
        float v3 = ts[(size_t)s3 * 16 + c];
        float v4 = ts[(size_t)s4 * 16 + c];
        float v5 = ts[(size_t)s5 * 16 + c];
        float v6 = ts[(size_t)s6 * 16 + c];
        float v7 = ts[(size_t)s7 * 16 + c];
        acc += ((v0 + v1) + (v2 + v3)) + ((v4 + v5) + (v6 + v7));
    }
    for (; j + 4 <= r1; j += 4) {
        int s0 = csr[j], s1 = csr[j + 1], s2 = csr[j + 2], s3 = csr[j + 3];
        float v0 = ts[(size_t)s0 * 16 + c];
        float v1 = ts[(size_t)s1 * 16 + c];
        float v2 = ts[(size_t)s2 * 16 + c];
        float v3 = ts[(size_t)s3 * 16 + c];
        acc += (v0 + v1) + (v2 + v3);
    }
    for (; j < r1; ++j) acc += ts[(size_t)csr[j] * 16 + c];
    if (c < N_CLASS) out[(size_t)n * N_CLASS + c] = dinv[n] * acc + b2[c];
}

extern "C" void kernel_launch(void* const* d_in, const int* in_sizes, int n_in,
                              void* d_out, int out_size, void* d_ws, size_t ws_size,
                              hipStream_t stream) {
    const float* x  = (const float*)d_in[0];   // fp32 [N,512]
    const void*  ei = d_in[1];                 // int64 (int32 handled via probe)
    const float* W1 = (const float*)d_in[2];   // fp32 [512,16]
    const float* b1 = (const float*)d_in[3];   // fp32 [16]
    const float* W2 = (const float*)d_in[4];   // fp32 [16,10]
    const float* b2 = (const float*)d_in[5];   // fp32 [10]
    float* out = (float*)d_out;                // fp32 [N,10]
    float* ws  = (float*)d_ws;

    // ws layout (4-byte units), ~26.4 MB total
    float* dinv   = ws;                        // 100,096
    int*   rowptr = (int*)(ws + 100096);       // 100,416  (N+1, padded)
    int*   bsize  = (int*)(ws + 200512);       // 256
    int*   bbase  = (int*)(ws + 200768);       // 256
    int*   bcur   = (int*)(ws + 201024);       // 256
    int*   det    = (int*)(ws + 201280);       // 64
    int*   csr    = (int*)(ws + 201344);       // 3,200,000
    float* hs     = ws + 3401344;              // 1,600,000
    float* ts     = ws + 5001344;              // 1,600,000
    // buf (3.2M uint32) overlays hs+ts: dead after k_place3, before k_gemv1 writes hs
    unsigned* buf = (unsigned*)(ws + 3401344);

    k_init      <<<1, 256, 0, stream>>>((const unsigned*)ei, bsize, det);
    k_bhist     <<<NPART, 256, 0, stream>>>(ei, det, bsize);
    k_bucketscan<<<1, 256, 0, stream>>>(bsize, bbase, bcur);
    k_part      <<<NPART, 256, 0, stream>>>(ei, det, bcur, buf);
    k_degscan   <<<NBUCK, 256, 0, stream>>>(buf, bbase, bsize, rowptr, dinv);
    k_place3    <<<NBUCK, 256, 0, stream>>>(buf, bbase, bsize, rowptr, csr);

    k_gemv1<<<(N_NODES + 63) / 64, 256, 0, stream>>>(x, W1, dinv, hs);

    k_agg1<<<(N_NODES + 15) / 16, 256, 0, stream>>>(rowptr, csr, hs, dinv, b1, W2, ts);
    k_agg2<<<(N_NODES + 15) / 16, 256, 0, stream>>>(rowptr, csr, ts, dinv, b2, out);
}

// Round 10
// 521.659 us; speedup vs baseline: 1.1620x; 1.1226x over previous
//
#include <hip/hip_runtime.h>

#define N_NODES 100000
#define N_EDGES 3200000
#define F_IN    512
#define HIDDEN  16
#define N_CLASS 10

#define TILE_R  64
#define KC      64
#define XSTRIDE 68   // padded LDS stride (floats); %4==0 for b128, measured 0 bank conflicts

#define NBUCK   196       // dst buckets of 512 nodes: 196*512 = 100352 >= N_NODES
#define BSH     9         // bucket shift (512 nodes)
#define EPB     4096      // edges per partition block
#define NPART   ((N_EDGES + EPB - 1) / EPB)   // 782
#define PCAP    18432     // LDS staging cap per bucket (mean 16326 + 16 sigma; guarded fallback)

// index load robust to int32/int64 (is32 nonzero => int32)
__device__ __forceinline__ int load_idx(const void* ei, int is32, long long pos) {
    return is32 ? ((const int*)ei)[pos] : (int)((const long long*)ei)[pos];
}

// merged init: zero bucket sizes + int32/int64 probe (single block)
__global__ void k_init(const unsigned* __restrict__ ei, int* __restrict__ bsize,
                       int* __restrict__ det) {
    int t = threadIdx.x;
    if (t < NBUCK) bsize[t] = 0;
    if (t == 0) det[0] = 0;
    __syncthreads();
    unsigned odd = 0;
    for (int i = t; i < 4096; i += 256) odd |= ei[2 * i + 1];   // 32KB read, safe either way
    if (odd) atomicOr(&det[0], 1);
}

// per-block LDS histogram of dst buckets -> global bucket sizes
__global__ __launch_bounds__(256) void k_bhist(const void* __restrict__ ei,
                                               const int* __restrict__ det,
                                               int* __restrict__ bsize) {
    __shared__ int hist[NBUCK];
    int t = threadIdx.x;
    long long e0 = (long long)blockIdx.x * EPB;
    long long e1 = e0 + EPB; if (e1 > N_EDGES) e1 = N_EDGES;
    int is32 = det[0];
    if (t < NBUCK) hist[t] = 0;
    __syncthreads();
    for (long long e = e0 + t; e < e1; e += 256) {
        int d = load_idx(ei, is32, N_EDGES + e);
        atomicAdd(&hist[d >> BSH], 1);
    }
    __syncthreads();
    if (t < NBUCK && hist[t]) atomicAdd(&bsize[t], hist[t]);
}

// exclusive scan of 196 bucket sizes -> bbase (read-only) and bcur (atomic cursors)
__global__ void k_bucketscan(const int* __restrict__ bsize, int* __restrict__ bbase,
                             int* __restrict__ bcur) {
    __shared__ int s[256];
    int t = threadIdx.x;
    int v = (t < NBUCK) ? bsize[t] : 0;
    s[t] = v;
    __syncthreads();
    for (int off = 1; off < 256; off <<= 1) {
        int u = (t >= off) ? s[t - off] : 0;
        __syncthreads();
        s[t] += u;
        __syncthreads();
    }
    if (t < NBUCK) { int ex = s[t] - v; bbase[t] = ex; bcur[t] = ex; }
}

// partition edges into dst buckets; packed word = (s<<9)|(d&511) (26 bits)
__global__ __launch_bounds__(256) void k_part(const void* __restrict__ ei,
                                              const int* __restrict__ det,
                                              int* __restrict__ bcur,
                                              unsigned* __restrict__ buf) {
    __shared__ int hist[NBUCK];
    __shared__ int base[NBUCK];
    __shared__ int lcur[NBUCK];
    int t = threadIdx.x;
    long long e0 = (long long)blockIdx.x * EPB;
    long long e1 = e0 + EPB; if (e1 > N_EDGES) e1 = N_EDGES;
    int is32 = det[0];
    if (t < NBUCK) { hist[t] = 0; lcur[t] = 0; }
    __syncthreads();
    for (long long e = e0 + t; e < e1; e += 256) {
        int d = load_idx(ei, is32, N_EDGES + e);
        atomicAdd(&hist[d >> BSH], 1);
    }
    __syncthreads();
    if (t < NBUCK) base[t] = hist[t] ? atomicAdd(&bcur[t], hist[t]) : 0;
    __syncthreads();
    for (long long e = e0 + t; e < e1; e += 256) {
        int s = load_idx(ei, is32, e);
        int d = load_idx(ei, is32, (long long)N_EDGES + e);
        int b = d >> BSH;
        int off = atomicAdd(&lcur[b], 1);
        buf[base[b] + off] = ((unsigned)s << BSH) | (unsigned)(d & 511);
    }
}

// per-bucket degree histogram + in-LDS 512-wide scan -> rowptr AND dinv in one pass.
// Invariant: bbase[b] == rowptr[b<<BSH] (both prefix-sum the same per-bucket counts).
__global__ __launch_bounds__(256) void k_degscan(const unsigned* __restrict__ buf,
                                                 const int* __restrict__ bbase,
                                                 const int* __restrict__ bsize,
                                                 int* __restrict__ rowptr,
                                                 float* __restrict__ dinv) {
    __shared__ int s[512];
    int t = threadIdx.x;
    int b = blockIdx.x;
    s[t] = 0; s[t + 256] = 0;
    __syncthreads();
    int j0 = bbase[b], j1 = j0 + bsize[b];
    for (int j = j0 + t; j < j1; j += 256)
        atomicAdd(&s[buf[j] & 511], 1);
    __syncthreads();
    int o0 = s[t], o1 = s[t + 256];
    // inclusive Hillis-Steele over 512 elems, 2 per thread (read-all / barrier / write-all)
    for (int off = 1; off < 512; off <<= 1) {
        int v0 = (t >= off) ? s[t - off] : 0;
        int v1 = s[t + 256 - off];           // t+256 >= off always (off <= 256)
        __syncthreads();
        s[t] += v0; s[t + 256] += v1;
        __syncthreads();
    }
    int nb0 = b << BSH;
    int base = bbase[b];
    int n0 = nb0 + t, n1 = nb0 + t + 256;
    if (n0 < N_NODES) { rowptr[n0] = base + s[t] - o0;       dinv[n0] = rsqrtf((float)(o0 + 1)); }
    if (n1 < N_NODES) { rowptr[n1] = base + s[t + 256] - o1; dinv[n1] = rsqrtf((float)(o1 + 1)); }
    if (b == NBUCK - 1 && t == 0) rowptr[N_NODES] = N_EDGES;
}

// CSR placement with LDS staging: one block per bucket; coalesced csr stores.
__global__ __launch_bounds__(256) void k_place3(const unsigned* __restrict__ buf,
                                                const int* __restrict__ bbase,
                                                const int* __restrict__ bsize,
                                                const int* __restrict__ rowptr,
                                                int* __restrict__ csr) {
    __shared__ int lptr[512];
    __shared__ int outb[PCAP];
    int t = threadIdx.x;
    int b = blockIdx.x;
    int jb = bbase[b];           // buf segment base
    int sz = bsize[b];
    int nb0 = b << BSH;
    int csrbase = rowptr[nb0];   // == jb
    for (int i = t; i < 512; i += 256) {
        int n = nb0 + i;
        lptr[i] = (n < N_NODES) ? rowptr[n] - csrbase : sz;
    }
    __syncthreads();
    for (int j = t; j < sz; j += 256) {
        unsigned p = buf[jb + j];
        int pos = atomicAdd(&lptr[p & 511], 1);
        int s = (int)(p >> BSH);
        if (pos < PCAP) outb[pos] = s;
        else            csr[csrbase + pos] = s;   // statistically unreachable fallback
    }
    __syncthreads();
    int lim = sz < PCAP ? sz : PCAP;
    for (int j = t; j < lim; j += 256) csr[csrbase + j] = outb[j];
}

// W1 [512][16] -> Wt [16][512]
__global__ void k_wt(const float* __restrict__ W1, float* __restrict__ Wt) {
    int t = blockIdx.x * 256 + threadIdx.x;
    if (t < F_IN * HIDDEN) {
        int k = t >> 9;
        int j = t & (F_IN - 1);
        Wt[t] = W1[j * HIDDEN + k];
    }
}

// hs[N][16] = (x @ W1) * dinv[row].
// 64-row tile (17.4KB LDS), 1563 blocks (~7/CU), register-prefetch pipeline:
// chunk ch+1's global loads issue before chunk ch's compute -> HBM latency hides.
// [measured r7: below 120us top-5 cutoff; VGPR ~72, cross-block TLP covers barriers]
__global__ __launch_bounds__(256) void k_gemm1(const float* __restrict__ x,
                                               const float* __restrict__ Wt,
                                               const float* __restrict__ dinv,
                                               float* __restrict__ hs) {
    __shared__ float sX[TILE_R * XSTRIDE];
    int t = threadIdx.x;
    int lane = t & 63;
    int rowbase = blockIdx.x * TILE_R;
    int kbase = __builtin_amdgcn_readfirstlane((t >> 6) << 2);   // 0,4,8,12
    const float* wk = Wt + kbase * F_IN;

    // staging map: f = i*256+t in 0..1023; row=f>>4 (0..63), c4=f&15
    float4 r[4];
#pragma unroll
    for (int i = 0; i < 4; ++i) {
        int f = i * 256 + t, row = f >> 4, c4 = f & 15;
        int grow = rowbase + row;
        r[i] = make_float4(0.f, 0.f, 0.f, 0.f);
        if (grow < N_NODES)
            r[i] = ((const float4*)(x + (size_t)grow * F_IN))[c4];
    }
    float acc[4] = {};
#pragma unroll 1
    for (int ch = 0; ch < F_IN / KC; ++ch) {
        // store staged regs to LDS
#pragma unroll
        for (int i = 0; i < 4; ++i) {
            int f = i * 256 + t, row = f >> 4, c4 = f & 15;
            *((float4*)&sX[row * XSTRIDE + c4 * 4]) = r[i];
        }
        __syncthreads();
        // prefetch next chunk into regs (overlaps with compute below)
        if (ch + 1 < F_IN / KC) {
#pragma unroll
            for (int i = 0; i < 4; ++i) {
                int f = i * 256 + t, row = f >> 4, c4 = f & 15;
                int grow = rowbase + row;
                r[i] = make_float4(0.f, 0.f, 0.f, 0.f);
                if (grow < N_NODES)
                    r[i] = ((const float4*)(x + (size_t)grow * F_IN + (ch + 1) * KC))[c4];
            }
        }
        // compute: lane owns row `lane`; wave owns cols kbase..kbase+3 (W wave-uniform -> s_load)
#pragma unroll
        for (int js = 0; js < KC; js += 4) {
            float4 xv = *((const float4*)&sX[lane * XSTRIDE + js]);
#pragma unroll
            for (int kk = 0; kk < 4; ++kk) {
                const float* wp = wk + kk * F_IN + ch * KC + js;
                acc[kk] += xv.x * wp[0] + xv.y * wp[1] + xv.z * wp[2] + xv.w * wp[3];
            }
        }
        __syncthreads();   // all reads done before next iteration's store
    }
    int grow = rowbase + lane;
    if (grow < N_NODES) {
        float di = dinv[grow];
        *((float4*)&hs[(size_t)grow * HIDDEN + kbase]) =
            make_float4(acc[0] * di, acc[1] * di, acc[2] * di, acc[3] * di);
    }
}

// layer-1 gather-aggregate (atomic-free) + bias + ReLU + (16->10)W2 + dinv pre-scale.
// 8-deep gather unroll: 8 independent L2/L3 loads in flight per 16-lane group.
__global__ __launch_bounds__(256) void k_agg1(const int* __restrict__ rowptr,
                                              const int* __restrict__ csr,
                                              const float* __restrict__ hs,
                                              const float* __restrict__ dinv,
                                              const float* __restrict__ b1,
                                              const float* __restrict__ W2,
                                              float* __restrict__ ts) {
    __shared__ float sh[16][17];
    int t  = threadIdx.x;
    int ln = t >> 4;          // local node 0..15
    int k  = t & 15;          // feature lane
    int n  = blockIdx.x * 16 + ln;
    bool valid = n < N_NODES;
    int r0 = valid ? rowptr[n] : 0;
    int r1 = valid ? rowptr[n + 1] : 0;
    float acc = valid ? hs[(size_t)n * HIDDEN + k] : 0.f;   // self-loop (already *dinv[n])
    int j = r0;
    for (; j + 8 <= r1; j += 8) {
        int s0 = csr[j],     s1 = csr[j + 1], s2 = csr[j + 2], s3 = csr[j + 3];
        int s4 = csr[j + 4], s5 = csr[j + 5], s6 = csr[j + 6], s7 = csr[j + 7];
        float v0 = hs[(size_t)s0 * HIDDEN + k];
        float v1 = hs[(size_t)s1 * HIDDEN + k];
        float v2 = hs[(size_t)s2 * HIDDEN + k];
        float v3 = hs[(size_t)s3 * HIDDEN + k];
        float v4 = hs[(size_t)s4 * HIDDEN + k];
        float v5 = hs[(size_t)s5 * HIDDEN + k];
        float v6 = hs[(size_t)s6 * HIDDEN + k];
        float v7 = hs[(size_t)s7 * HIDDEN + k];
        acc += ((v0 + v1) + (v2 + v3)) + ((v4 + v5) + (v6 + v7));
    }
    for (; j + 4 <= r1; j += 4) {
        int s0 = csr[j], s1 = csr[j + 1], s2 = csr[j + 2], s3 = csr[j + 3];
        float v0 = hs[(size_t)s0 * HIDDEN + k];
        float v1 = hs[(size_t)s1 * HIDDEN + k];
        float v2 = hs[(size_t)s2 * HIDDEN + k];
        float v3 = hs[(size_t)s3 * HIDDEN + k];
        acc += (v0 + v1) + (v2 + v3);
    }
    for (; j < r1; ++j) acc += hs[(size_t)csr[j] * HIDDEN + k];
    float di = valid ? dinv[n] : 0.f;
    float h = di * acc + b1[k];
    sh[ln][k] = h > 0.f ? h : 0.f;
    __syncthreads();
    int c = (k < N_CLASS) ? k : 0;
    float o = 0.f;
#pragma unroll
    for (int kk = 0; kk < HIDDEN; ++kk) o += sh[ln][kk] * W2[kk * N_CLASS + c];
    if (valid) ts[(size_t)n * 16 + k] = (k < N_CLASS) ? o * di : 0.f;
}

// layer-2 gather-aggregate (atomic-free) + bias -> out
__global__ __launch_bounds__(256) void k_agg2(const int* __restrict__ rowptr,
                                              const int* __restrict__ csr,
                                              const float* __restrict__ ts,
                                              const float* __restrict__ dinv,
                                              const float* __restrict__ b2,
                                              float* __restrict__ out) {
    int t  = threadIdx.x;
    int ln = t >> 4;
    int c  = t & 15;
    int n  = blockIdx.x * 16 + ln;
    if (n >= N_NODES) return;
    int r0 = rowptr[n], r1 = rowptr[n + 1];
    float acc = ts[(size_t)n * 16 + c];    // self-loop (already *dinv[n])
    int j = r0;
    for (; j + 8 <= r1; j += 8) {
        int s0 = csr[j],     s1 = csr[j + 1], s2 = csr[j + 2], s3 = csr[j + 3];
        int s4 = csr[j + 4], s5 = csr[j + 5], s6 = csr[j + 6], s7 = csr[j + 7];
        float v0 = ts[(size_t)s0 * 16 + c];
        float v1 = ts[(size_t)s1 * 16 + c];
        float v2 = ts[(size_t)s2 * 16 + c];
        float v3 = ts[(size_t)s3 * 16 + c];
        float v4 = ts[(size_t)s4 * 16 + c];
        float v5 = ts[(size_t)s5 * 16 + c];
        float v6 = ts[(size_t)s6 * 16 + c];
        float v7 = ts[(size_t)s7 * 16 + c];
        acc += ((v0 + v1) + (v2 + v3)) + ((v4 + v5) + (v6 + v7));
    }
    for (; j + 4 <= r1; j += 4) {
        int s0 = csr[j], s1 = csr[j + 1], s2 = csr[j + 2], s3 = csr[j + 3];
        float v0 = ts[(size_t)s0 * 16 + c];
        float v1 = ts[(size_t)s1 * 16 + c];
        float v2 = ts[(size_t)s2 * 16 + c];
        float v3 = ts[(size_t)s3 * 16 + c];
        acc += (v0 + v1) + (v2 + v3);
    }
    for (; j < r1; ++j) acc += ts[(size_t)csr[j] * 16 + c];
    if (c < N_CLASS) out[(size_t)n * N_CLASS + c] = dinv[n] * acc + b2[c];
}

extern "C" void kernel_launch(void* const* d_in, const int* in_sizes, int n_in,
                              void* d_out, int out_size, void* d_ws, size_t ws_size,
                              hipStream_t stream) {
    const float* x  = (const float*)d_in[0];   // fp32 [N,512]
    const void*  ei = d_in[1];                 // int64 (int32 handled via probe)
    const float* W1 = (const float*)d_in[2];   // fp32 [512,16]
    const float* b1 = (const float*)d_in[3];   // fp32 [16]
    const float* W2 = (const float*)d_in[4];   // fp32 [16,10]
    const float* b2 = (const float*)d_in[5];   // fp32 [10]
    float* out = (float*)d_out;                // fp32 [N,10]
    float* ws  = (float*)d_ws;

    // ws layout (4-byte units), ~26.4 MB total
    float* dinv   = ws;                        // 100,096
    int*   rowptr = (int*)(ws + 100096);       // 100,416  (N+1, padded)
    int*   bsize  = (int*)(ws + 200512);       // 256
    int*   bbase  = (int*)(ws + 200768);       // 256
    int*   bcur   = (int*)(ws + 201024);       // 256
    int*   det    = (int*)(ws + 201280);       // 64
    int*   csr    = (int*)(ws + 201344);       // 3,200,000
    float* hs     = ws + 3401344;              // 1,600,000
    float* ts     = ws + 5001344;              // 1,600,000
    float* Wt     = ws + 6601344;              // 8,192
    // buf (3.2M uint32) overlays hs+ts: dead after k_place3, before k_gemm1 writes hs
    unsigned* buf = (unsigned*)(ws + 3401344);

    k_init      <<<1, 256, 0, stream>>>((const unsigned*)ei, bsize, det);
    k_bhist     <<<NPART, 256, 0, stream>>>(ei, det, bsize);
    k_bucketscan<<<1, 256, 0, stream>>>(bsize, bbase, bcur);
    k_part      <<<NPART, 256, 0, stream>>>(ei, det, bcur, buf);
    k_degscan   <<<NBUCK, 256, 0, stream>>>(buf, bbase, bsize, rowptr, dinv);
    k_place3    <<<NBUCK, 256, 0, stream>>>(buf, bbase, bsize, rowptr, csr);

    k_wt   <<<(F_IN * HIDDEN) / 256, 256, 0, stream>>>(W1, Wt);
    k_gemm1<<<(N_NODES + TILE_R - 1) / TILE_R, 256, 0, stream>>>(x, Wt, dinv, hs);

    k_agg1<<<(N_NODES + 15) / 16, 256, 0, stream>>>(rowptr, csr, hs, dinv, b1, W2, ts);
    k_agg2<<<(N_NODES + 15) / 16, 256, 0, stream>>>(rowptr, csr, ts, dinv, b2, out);
}